// Round 2
// baseline (1646.407 us; speedup 1.0000x reference)
//
#include <hip/hip_runtime.h>

#define FDIM 128
#define NEDGE 640000
#define NNODE 10000
#define K1PAD 160   // edge MLP layer-1 padded K (128 s + 20 rbf + 12 zero)
#define HSTR 136    // LDS h-tile row stride in bf16 elems (272B = 17*16B, aligned)

typedef __attribute__((ext_vector_type(8))) short short8;   // 8 x bf16 (4 VGPRs)
typedef __attribute__((ext_vector_type(4))) float f32x4;
typedef __attribute__((ext_vector_type(4))) unsigned short ushort4_t;

static __device__ __forceinline__ unsigned short f2bf(float f){
  unsigned int u = __builtin_bit_cast(unsigned int, f);
  u += 0x7fffu + ((u >> 16) & 1u);           // RNE
  return (unsigned short)(u >> 16);
}
static __device__ __forceinline__ short8 pack8(const float* x){
  short8 r;
#pragma unroll
  for (int i = 0; i < 8; ++i) r[i] = (short)f2bf(x[i]);
  return r;
}
static __device__ __forceinline__ short8 cvt8(float4 a, float4 b){
  float x[8] = {a.x, a.y, a.z, a.w, b.x, b.y, b.z, b.w};
  return pack8(x);
}
static __device__ __forceinline__ f32x4 mfma16(short8 a, short8 b, f32x4 c){
  return __builtin_amdgcn_mfma_f32_16x16x32_bf16(a, b, c, 0, 0, 0);
}
static __device__ __forceinline__ float silu(float p){
  return p * (1.f / (1.f + __expf(-p)));
}

// ---------------- prep: transpose + bf16-convert all 8 weight matrices ----------------
// ws weight buffer layout (ushort offsets):
//   msW1T 0      [128][160]   mvW1T 20480 [128][160]
//   msW2T 40960  [128][128]   mvW2T 57344 [128][128]
//   usW1T 73728  [128][256]   uvW1T 106496[128][256]
//   usW2T 139264 [128][128]   uvW2T 155648[128][128]     total 172032
__global__ __launch_bounds__(256) void prep_wt(
    const float* __restrict__ ms_w1, const float* __restrict__ mv_w1,
    const float* __restrict__ ms_w2, const float* __restrict__ mv_w2,
    const float* __restrict__ us_w1, const float* __restrict__ uv_w1,
    const float* __restrict__ us_w2, const float* __restrict__ uv_w2,
    unsigned short* __restrict__ wbuf)
{
  int i = blockIdx.x * 256 + threadIdx.x;
  if (i >= 172032) return;
  float val;
  if (i < 40960) {                       // W1T edge MLPs, K=148 pad 160
    int t = (i < 20480) ? i : i - 20480;
    const float* src = (i < 20480) ? ms_w1 : mv_w1;
    int j = t / 160, k = t - j * 160;
    val = (k < 148) ? src[k * 128 + j] : 0.f;
  } else if (i < 73728) {                // W2T edge MLPs, 128x128
    int t = i - 40960;
    const float* src = (t < 16384) ? ms_w2 : mv_w2;
    t &= 16383;
    int j = t >> 7, k = t & 127;
    val = src[k * 128 + j];
  } else if (i < 139264) {               // W1T node MLPs, K=256
    int t = i - 73728;
    const float* src = (t < 32768) ? us_w1 : uv_w1;
    t &= 32767;
    int j = t >> 8, k = t & 255;
    val = src[k * 128 + j];
  } else {                               // W2T node MLPs
    int t = i - 139264;
    const float* src = (t < 16384) ? us_w2 : uv_w2;
    t &= 16383;
    int j = t >> 7, k = t & 127;
    val = src[k * 128 + j];
  }
  wbuf[i] = f2bf(val);
}

// ---------------- prep: s -> bf16, zero ds_agg+dv_agg (contiguous 5.12M floats) ------
__global__ __launch_bounds__(256) void prep_misc(
    const float* __restrict__ s, unsigned short* __restrict__ s_bf,
    float* __restrict__ zero_base)
{
  int i = blockIdx.x * 256 + threadIdx.x;   // 1,600,000 total, 4 elems each
  if (i < 320000) {
    float4 p = *reinterpret_cast<const float4*>(s + i * 4);
    ushort4_t o;
    o[0] = f2bf(p.x); o[1] = f2bf(p.y); o[2] = f2bf(p.z); o[3] = f2bf(p.w);
    *reinterpret_cast<ushort4_t*>(s_bf + i * 4) = o;
  } else {
    int t = i - 320000;                     // 0..1,279,999 -> 5.12M floats
    float4 z = {0.f, 0.f, 0.f, 0.f};
    *reinterpret_cast<float4*>(zero_base + t * 4) = z;
  }
}

// ---------------- shared MLP core: x[2 subtiles of 16 rows][K] -> acc2 (pre-bias) ----
// afrag: A-fragments for 5 k-steps (K1PAD=160). W1:[128][160] W2:[128][128] bf16.
__device__ __forceinline__ void run_mlp_edge(
    const short8 (&afrag)[2][5],
    const unsigned short* __restrict__ W1, const float* __restrict__ B1,
    const unsigned short* __restrict__ W2,
    unsigned short* hb, int g, int r16, f32x4 (&acc2)[2][8])
{
  f32x4 acc[2][8];
  const f32x4 z = {0.f, 0.f, 0.f, 0.f};
#pragma unroll
  for (int es = 0; es < 2; ++es)
#pragma unroll
    for (int nt = 0; nt < 8; ++nt) acc[es][nt] = z;
#pragma unroll
  for (int ks = 0; ks < 5; ++ks) {
#pragma unroll
    for (int nt = 0; nt < 8; ++nt) {
      const short8 w = *reinterpret_cast<const short8*>(W1 + (nt * 16 + r16) * K1PAD + ks * 32 + g * 8);
      acc[0][nt] = mfma16(afrag[0][ks], w, acc[0][nt]);
      acc[1][nt] = mfma16(afrag[1][ks], w, acc[1][nt]);
    }
  }
  float b1v[8];
#pragma unroll
  for (int nt = 0; nt < 8; ++nt) b1v[nt] = B1[nt * 16 + r16];
  // SiLU + transpose through LDS: D layout is (col=lane&15 -> out j, row=(lane>>4)*4+r -> edge)
#pragma unroll
  for (int es = 0; es < 2; ++es)
#pragma unroll
    for (int nt = 0; nt < 8; ++nt)
#pragma unroll
      for (int r = 0; r < 4; ++r) {
        float p = acc[es][nt][r] + b1v[nt];
        hb[(es * 16 + g * 4 + r) * HSTR + nt * 16 + r16] = f2bf(silu(p));
      }
#pragma unroll
  for (int es = 0; es < 2; ++es)
#pragma unroll
    for (int nt = 0; nt < 8; ++nt) acc2[es][nt] = z;
#pragma unroll
  for (int ks = 0; ks < 4; ++ks) {
    const short8 a0 = *reinterpret_cast<const short8*>(hb + r16 * HSTR + ks * 32 + g * 8);
    const short8 a1 = *reinterpret_cast<const short8*>(hb + (16 + r16) * HSTR + ks * 32 + g * 8);
#pragma unroll
    for (int nt = 0; nt < 8; ++nt) {
      const short8 w = *reinterpret_cast<const short8*>(W2 + (nt * 16 + r16) * FDIM + ks * 32 + g * 8);
      acc2[0][nt] = mfma16(a0, w, acc2[0][nt]);
      acc2[1][nt] = mfma16(a1, w, acc2[1][nt]);
    }
  }
}

// ---------------- edge kernel: per-edge ms/mv MLPs + atomic aggregation --------------
__global__ __launch_bounds__(256) void edge_kernel(
    const float* __restrict__ v,
    const int* __restrict__ erow, const int* __restrict__ ecol,
    const float* __restrict__ rbf,
    const unsigned short* __restrict__ s_bf,
    const unsigned short* __restrict__ wms1, const unsigned short* __restrict__ wms2,
    const float* __restrict__ ms_b1, const float* __restrict__ ms_b2,
    const unsigned short* __restrict__ wmv1, const unsigned short* __restrict__ wmv2,
    const float* __restrict__ mv_b1, const float* __restrict__ mv_b2,
    float* __restrict__ ds_agg, float* __restrict__ dv_agg)
{
  __shared__ unsigned short lds_h[4][32 * HSTR];   // per-wave private h tiles (34,816 B)
  const int tid = threadIdx.x;
  const int wid = tid >> 6, lane = tid & 63;
  const int g = lane >> 4, r16 = lane & 15;
  const int e0 = blockIdx.x * 128 + wid * 32;      // wave owns 32 edges
  unsigned short* hb = &lds_h[wid][0];

  // ---- A fragments: x = [s_row | rbf | pad] in bf16 (shared by both MLPs) ----
  short8 afrag[2][5];
#pragma unroll
  for (int es = 0; es < 2; ++es) {
    const int e = e0 + es * 16 + r16;
    const int rA = erow[e];
    const unsigned short* sp = s_bf + rA * FDIM + g * 8;
#pragma unroll
    for (int ks = 0; ks < 4; ++ks)
      afrag[es][ks] = *reinterpret_cast<const short8*>(sp + ks * 32);
    float xr[8] = {0.f, 0.f, 0.f, 0.f, 0.f, 0.f, 0.f, 0.f};
    if (g < 2) {
      float4 p0 = *reinterpret_cast<const float4*>(rbf + e * 20 + g * 8);
      float4 p1 = *reinterpret_cast<const float4*>(rbf + e * 20 + g * 8 + 4);
      xr[0] = p0.x; xr[1] = p0.y; xr[2] = p0.z; xr[3] = p0.w;
      xr[4] = p1.x; xr[5] = p1.y; xr[6] = p1.z; xr[7] = p1.w;
    } else if (g == 2) {
      float4 p0 = *reinterpret_cast<const float4*>(rbf + e * 20 + 16);
      xr[0] = p0.x; xr[1] = p0.y; xr[2] = p0.z; xr[3] = p0.w;
    }
    afrag[es][4] = pack8(xr);
  }
  // epilogue edge ids: D rows map edge = es*16 + g*4 + r
  int dstE[2][4], rowE[2][4];
#pragma unroll
  for (int es = 0; es < 2; ++es)
#pragma unroll
    for (int r = 0; r < 4; ++r) {
      const int e = e0 + es * 16 + g * 4 + r;
      dstE[es][r] = ecol[e];
      rowE[es][r] = erow[e];
    }

  // ---- ms MLP -> ds, atomic scatter ----
  {
    f32x4 acc2[2][8];
    run_mlp_edge(afrag, wms1, ms_b1, wms2, hb, g, r16, acc2);
    float b2v[8];
#pragma unroll
    for (int nt = 0; nt < 8; ++nt) b2v[nt] = ms_b2[nt * 16 + r16];
#pragma unroll
    for (int es = 0; es < 2; ++es)
#pragma unroll
      for (int r = 0; r < 4; ++r) {
        float* dsa = ds_agg + dstE[es][r] * FDIM;
#pragma unroll
        for (int nt = 0; nt < 8; ++nt)
          unsafeAtomicAdd(dsa + nt * 16 + r16, acc2[es][nt][r] + b2v[nt]);
      }
  }
  // ---- mv MLP -> dv = mlp * v_diff/(|v_diff|+eps), atomic scatter ----
  {
    f32x4 acc2[2][8];
    run_mlp_edge(afrag, wmv1, mv_b1, wmv2, hb, g, r16, acc2);
    float b2v[8];
#pragma unroll
    for (int nt = 0; nt < 8; ++nt) b2v[nt] = mv_b2[nt * 16 + r16];
#pragma unroll
    for (int es = 0; es < 2; ++es)
#pragma unroll
      for (int r = 0; r < 4; ++r) {
        const float* vr = v + (long)rowE[es][r] * 384;
        const float* vc = v + (long)dstE[es][r] * 384;
        float* dva = dv_agg + dstE[es][r] * 384;
#pragma unroll
        for (int nt = 0; nt < 8; ++nt) {
          const int j = nt * 16 + r16;
          float d0 = vr[j] - vc[j];
          float d1 = vr[j + 128] - vc[j + 128];
          float d2 = vr[j + 256] - vc[j + 256];
          float nrm = sqrtf(d0 * d0 + d1 * d1 + d2 * d2);
          float base = (acc2[es][nt][r] + b2v[nt]) / (nrm + 1e-8f);
          unsafeAtomicAdd(dva + j, base * d0);
          unsafeAtomicAdd(dva + j + 128, base * d1);
          unsafeAtomicAdd(dva + j + 256, base * d2);
        }
      }
  }
}

// ---------------- node kernel: out = resid + MLP([xin | agg]), f32 store -------------
__global__ __launch_bounds__(256) void node_kernel(
    const float* __restrict__ xin,           // [rows][128] f32 (also residual)
    const float* __restrict__ agg,           // [rows][128] f32
    const unsigned short* __restrict__ W1T,  // [128][256] bf16
    const float* __restrict__ b1,
    const unsigned short* __restrict__ W2T,  // [128][128] bf16
    const float* __restrict__ b2,
    float* __restrict__ outp,                // [rows][128] f32
    int nrows)
{
  __shared__ unsigned short lds_h[4][32 * HSTR];
  const int tid = threadIdx.x;
  const int wid = tid >> 6, lane = tid & 63;
  const int g = lane >> 4, r16 = lane & 15;
  const int n0 = blockIdx.x * 128 + wid * 32;
  unsigned short* hb = &lds_h[wid][0];

  short8 afrag[2][8];
#pragma unroll
  for (int es = 0; es < 2; ++es) {
    int n = n0 + es * 16 + r16;
    if (n >= nrows) n = nrows - 1;
    const float* xp = xin + (long)n * FDIM + g * 8;
    const float* ap = agg + (long)n * FDIM + g * 8;
#pragma unroll
    for (int ks = 0; ks < 4; ++ks) {
      float4 p0 = *reinterpret_cast<const float4*>(xp + ks * 32);
      float4 p1 = *reinterpret_cast<const float4*>(xp + ks * 32 + 4);
      afrag[es][ks] = cvt8(p0, p1);
    }
#pragma unroll
    for (int ks = 0; ks < 4; ++ks) {
      float4 p0 = *reinterpret_cast<const float4*>(ap + ks * 32);
      float4 p1 = *reinterpret_cast<const float4*>(ap + ks * 32 + 4);
      afrag[es][4 + ks] = cvt8(p0, p1);
    }
  }
  f32x4 acc[2][8];
  const f32x4 z = {0.f, 0.f, 0.f, 0.f};
#pragma unroll
  for (int es = 0; es < 2; ++es)
#pragma unroll
    for (int nt = 0; nt < 8; ++nt) acc[es][nt] = z;
#pragma unroll
  for (int ks = 0; ks < 8; ++ks) {
#pragma unroll
    for (int nt = 0; nt < 8; ++nt) {
      const short8 w = *reinterpret_cast<const short8*>(W1T + (nt * 16 + r16) * 256 + ks * 32 + g * 8);
      acc[0][nt] = mfma16(afrag[0][ks], w, acc[0][nt]);
      acc[1][nt] = mfma16(afrag[1][ks], w, acc[1][nt]);
    }
  }
  float b1v[8];
#pragma unroll
  for (int nt = 0; nt < 8; ++nt) b1v[nt] = b1[nt * 16 + r16];
#pragma unroll
  for (int es = 0; es < 2; ++es)
#pragma unroll
    for (int nt = 0; nt < 8; ++nt)
#pragma unroll
      for (int r = 0; r < 4; ++r) {
        float p = acc[es][nt][r] + b1v[nt];
        hb[(es * 16 + g * 4 + r) * HSTR + nt * 16 + r16] = f2bf(silu(p));
      }
  f32x4 acc2[2][8];
#pragma unroll
  for (int es = 0; es < 2; ++es)
#pragma unroll
    for (int nt = 0; nt < 8; ++nt) acc2[es][nt] = z;
#pragma unroll
  for (int ks = 0; ks < 4; ++ks) {
    const short8 a0 = *reinterpret_cast<const short8*>(hb + r16 * HSTR + ks * 32 + g * 8);
    const short8 a1 = *reinterpret_cast<const short8*>(hb + (16 + r16) * HSTR + ks * 32 + g * 8);
#pragma unroll
    for (int nt = 0; nt < 8; ++nt) {
      const short8 w = *reinterpret_cast<const short8*>(W2T + (nt * 16 + r16) * FDIM + ks * 32 + g * 8);
      acc2[0][nt] = mfma16(a0, w, acc2[0][nt]);
      acc2[1][nt] = mfma16(a1, w, acc2[1][nt]);
    }
  }
  float b2v[8];
#pragma unroll
  for (int nt = 0; nt < 8; ++nt) b2v[nt] = b2[nt * 16 + r16];
#pragma unroll
  for (int es = 0; es < 2; ++es)
#pragma unroll
    for (int r = 0; r < 4; ++r) {
      const int n = n0 + es * 16 + g * 4 + r;
      if (n < nrows) {
#pragma unroll
        for (int nt = 0; nt < 8; ++nt) {
          const int j = nt * 16 + r16;
          outp[(long)n * FDIM + j] = xin[(long)n * FDIM + j] + acc2[es][nt][r] + b2v[nt];
        }
      }
    }
}

extern "C" void kernel_launch(void* const* d_in, const int* in_sizes, int n_in,
                              void* d_out, int out_size, void* d_ws, size_t ws_size,
                              hipStream_t stream) {
  const float* s     = (const float*)d_in[0];
  const float* v     = (const float*)d_in[1];
  const int*   eidx  = (const int*)d_in[2];
  const float* rbf   = (const float*)d_in[3];
  const float* ms_w1 = (const float*)d_in[4];  const float* ms_b1 = (const float*)d_in[5];
  const float* ms_w2 = (const float*)d_in[6];  const float* ms_b2 = (const float*)d_in[7];
  const float* mv_w1 = (const float*)d_in[8];  const float* mv_b1 = (const float*)d_in[9];
  const float* mv_w2 = (const float*)d_in[10]; const float* mv_b2 = (const float*)d_in[11];
  const float* us_w1 = (const float*)d_in[12]; const float* us_b1 = (const float*)d_in[13];
  const float* us_w2 = (const float*)d_in[14]; const float* us_b2 = (const float*)d_in[15];
  const float* uv_w1 = (const float*)d_in[16]; const float* uv_b1 = (const float*)d_in[17];
  const float* uv_w2 = (const float*)d_in[18]; const float* uv_b2 = (const float*)d_in[19];

  char* ws = (char*)d_ws;
  float* ds_agg = (float*)(ws);                                // 1.28M f32
  float* dv_agg = (float*)(ws + 5120000);                      // 3.84M f32
  unsigned short* s_bf = (unsigned short*)(ws + 20480000);     // 1.28M bf16
  unsigned short* wbuf = (unsigned short*)(ws + 23040000);     // 172032 bf16

  prep_wt<<<672, 256, 0, stream>>>(ms_w1, mv_w1, ms_w2, mv_w2,
                                   us_w1, uv_w1, us_w2, uv_w2, wbuf);
  prep_misc<<<6250, 256, 0, stream>>>(s, s_bf, ds_agg);

  edge_kernel<<<5000, 256, 0, stream>>>(
      v, eidx, eidx + NEDGE, rbf, s_bf,
      wbuf + 0,      wbuf + 40960,  ms_b1, ms_b2,
      wbuf + 20480,  wbuf + 57344,  mv_b1, mv_b2,
      ds_agg, dv_agg);

  float* outp = (float*)d_out;
  node_kernel<<<79, 256, 0, stream>>>(s, ds_agg, wbuf + 73728, us_b1,
                                      wbuf + 139264, us_b2, outp, NNODE);
  node_kernel<<<235, 256, 0, stream>>>(v, dv_agg, wbuf + 106496, uv_b1,
                                       wbuf + 155648, uv_b2, outp + NNODE * FDIM, 3 * NNODE);
}